// Round 8
// baseline (581.459 us; speedup 1.0000x reference)
//
#include <hip/hip_runtime.h>

#define D        128
#define N_GRAPHS 64
#define N_CLS    16
#define LDA      40   // mm1m LDS row stride in bf16 (80 B: 16B-aligned, 2-way banks = free)
#define SLOTS    64   // padded CSR width; deg ~ Poisson(16), max<<64

typedef unsigned int  uint;
typedef unsigned short ushort;
typedef __attribute__((ext_vector_type(8))) short short8;
typedef __attribute__((ext_vector_type(4))) float f32x4;

__device__ inline ushort f2b(float f) {   // f32 -> bf16 RNE
    uint u = __float_as_uint(f);
    u += 0x7fffu + ((u >> 16) & 1u);
    return (ushort)(u >> 16);
}

// ---------------- padded-CSR build (no scan) ----------------

__global__ void k_degslot(const int* __restrict__ dst, int* __restrict__ deg,
                          int* __restrict__ slot, int E) {
    int e = blockIdx.x * 256 + threadIdx.x;
    if (e < E) slot[e] = atomicAdd(&deg[dst[e]], 1);
}

__global__ void k_prep(const int* __restrict__ deg, float* __restrict__ invdeg, int N) {
    int i = blockIdx.x * 256 + threadIdx.x;
    if (i < N) {
        int d = deg[i];
        invdeg[i] = 1.0f / (float)(d > 1 ? d : 1);
    }
}

__global__ void k_scatter(const int* __restrict__ src, const int* __restrict__ dst,
                          const int* __restrict__ slot, int* __restrict__ csrf, int E) {
    int e = blockIdx.x * 256 + threadIdx.x;
    if (e < E) {
        int sl = slot[e];
        if (sl < SLOTS) csrf[(size_t)dst[e] * SLOTS + sl] = src[e];
    }
}

// graph boundaries from sorted gid: gstart[g] = lower_bound(gid, g)
__global__ void k_gbound(const int* __restrict__ gid, int* __restrict__ gstart, int N) {
    int g = threadIdx.x;
    if (g > N_GRAPHS) return;
    int lo = 0, hi = N;
    while (lo < hi) {
        int mid = (lo + hi) >> 1;
        if (gid[mid] < g) lo = mid + 1; else hi = mid;
    }
    gstart[g] = lo;
}

// ---------------- casts ----------------

__global__ void k_cast(const float* __restrict__ x, ushort* __restrict__ y, int total4) {
    int i = blockIdx.x * 256 + threadIdx.x;
    if (i < total4) {
        float4 v = ((const float4*)x)[i];
        ushort4 o;
        o.x = f2b(v.x); o.y = f2b(v.y); o.z = f2b(v.z); o.w = f2b(v.w);
        ((ushort4*)y)[i] = o;
    }
}

// wT[col][k] (k=0..255: Ws rows then Wn rows), bf16
__global__ void k_castw(const float* __restrict__ Ws, const float* __restrict__ Wn,
                        ushort* __restrict__ wT) {
    int i = blockIdx.x * 256 + threadIdx.x;   // 32768
    int c = i >> 8, k = i & 255;
    float v = (k < 128) ? Ws[k * 128 + c] : Wn[(k - 128) * 128 + c];
    wT[c * 256 + k] = f2b(v);
}

// ---------------- quarter-split bf16 neighbor-mean gather ----------------
// quarter = blockIdx&3 (with XCD = blockIdx%8 round-robin, each XCD touches a
// 6.4 MB table slice -> L2-resident-ish). Wave per (node, quarter):
// lane = (ej 0..15, cg 0..3); each gather = one 64B line quarter-row slice;
// 16 edges in flight. shfl_xor(4,8,16,32) reduces; lanes 0-3 write bf16.

__global__ __launch_bounds__(256) void k_aggq(
    const ushort* __restrict__ fb, const int* __restrict__ deg,
    const int* __restrict__ csrf, const float* __restrict__ invdeg,
    ushort* __restrict__ outb, int N) {
    int q = blockIdx.x & 3;
    int n = (blockIdx.x >> 2) * 4 + (threadIdx.x >> 6);
    if (n >= N) return;
    int lane = threadIdx.x & 63;
    int ej = lane >> 2;      // 0..15
    int cg = lane & 3;       // cols q*32 + cg*8 .. +7
    int d  = deg[n];
    if (d > SLOTS) d = SLOTS;
    const int* __restrict__ lst = csrf + (size_t)n * SLOTS;

    float acc[8];
#pragma unroll
    for (int i = 0; i < 8; i++) acc[i] = 0.f;

    for (int e = ej; e < d; e += 16) {
        int s = lst[e];
        uint4 v = *(const uint4*)(fb + (size_t)s * D + q * 32 + cg * 8);
        acc[0] += __uint_as_float(v.x << 16);
        acc[1] += __uint_as_float(v.x & 0xffff0000u);
        acc[2] += __uint_as_float(v.y << 16);
        acc[3] += __uint_as_float(v.y & 0xffff0000u);
        acc[4] += __uint_as_float(v.z << 16);
        acc[5] += __uint_as_float(v.z & 0xffff0000u);
        acc[6] += __uint_as_float(v.w << 16);
        acc[7] += __uint_as_float(v.w & 0xffff0000u);
    }
#pragma unroll
    for (int i = 0; i < 8; i++) {
        acc[i] += __shfl_xor(acc[i], 4);
        acc[i] += __shfl_xor(acc[i], 8);
        acc[i] += __shfl_xor(acc[i], 16);
        acc[i] += __shfl_xor(acc[i], 32);
    }
    if (lane < 4) {          // ej==0, cg=lane
        float id = invdeg[n];
        uint4 o;
        o.x = (uint)f2b(acc[0] * id) | ((uint)f2b(acc[1] * id) << 16);
        o.y = (uint)f2b(acc[2] * id) | ((uint)f2b(acc[3] * id) << 16);
        o.z = (uint)f2b(acc[4] * id) | ((uint)f2b(acc[5] * id) << 16);
        o.w = (uint)f2b(acc[6] * id) | ((uint)f2b(acc[7] * id) << 16);
        *(uint4*)(outb + (size_t)n * D + q * 32 + lane * 8) = o;
    }
}

// ---------------- layer-1 GEMM via MFMA (bf16 in, bf16 out) ----------------

__global__ __launch_bounds__(256, 2) void k_mm1m(
    const ushort* __restrict__ hb, const ushort* __restrict__ nbb,
    const ushort* __restrict__ wT, const float* __restrict__ b,
    ushort* __restrict__ x1b, int N) {
    __shared__ __align__(16) ushort As[128 * LDA];
    __shared__ __align__(16) ushort Bs[128 * LDA];
    int t    = threadIdx.x;
    int w    = t >> 6;
    int lane = t & 63;
    int m    = lane & 15;
    int quad = lane >> 4;
    int n0   = blockIdx.x * 128;

    f32x4 acc[2][8];
#pragma unroll
    for (int rt = 0; rt < 2; rt++)
#pragma unroll
        for (int ct = 0; ct < 8; ct++) acc[rt][ct] = (f32x4){0.f, 0.f, 0.f, 0.f};

#pragma unroll 1
    for (int kc = 0; kc < 8; kc++) {
        int k0 = kc * 32;
        const ushort* __restrict__ A = (k0 < 128) ? hb : nbb;
        int ka = k0 & 127;
        __syncthreads();
#pragma unroll
        for (int i = 0; i < 2; i++) {
            int linear = i * 256 + t;       // 0..511
            int row = linear >> 2;
            int q   = linear & 3;
            int nn = n0 + row;
            uint4 v = make_uint4(0u, 0u, 0u, 0u);
            if (nn < N) v = *(const uint4*)(A + (size_t)nn * D + ka + q * 8);
            *(uint4*)(&As[row * LDA + q * 8]) = v;
        }
#pragma unroll
        for (int i = 0; i < 2; i++) {
            int linear = i * 256 + t;
            int col = linear >> 2;
            int q   = linear & 3;
            uint4 v = *(const uint4*)(wT + (size_t)col * 256 + k0 + q * 8);
            *(uint4*)(&Bs[col * LDA + q * 8]) = v;
        }
        __syncthreads();
        short8 af[2], bf[8];
#pragma unroll
        for (int rt = 0; rt < 2; rt++)
            af[rt] = *(const short8*)(&As[(w * 32 + rt * 16 + m) * LDA + quad * 8]);
#pragma unroll
        for (int ct = 0; ct < 8; ct++)
            bf[ct] = *(const short8*)(&Bs[(ct * 16 + m) * LDA + quad * 8]);
#pragma unroll
        for (int rt = 0; rt < 2; rt++)
#pragma unroll
            for (int ct = 0; ct < 8; ct++)
                acc[rt][ct] = __builtin_amdgcn_mfma_f32_16x16x32_bf16(
                    af[rt], bf[ct], acc[rt][ct], 0, 0, 0);
    }
#pragma unroll
    for (int ct = 0; ct < 8; ct++) {
        float bias = b[ct * 16 + m];
#pragma unroll
        for (int rt = 0; rt < 2; rt++) {
#pragma unroll
            for (int r = 0; r < 4; r++) {
                int n = n0 + w * 32 + rt * 16 + quad * 4 + r;
                if (n < N)
                    x1b[(size_t)n * D + ct * 16 + m] =
                        f2b(fmaxf(acc[rt][ct][r] + bias, 0.f));
            }
        }
    }
}

// ---------------- per-graph sums: contention-free via gstart ----------------

__global__ __launch_bounds__(256) void k_gsum(
    const ushort* __restrict__ x1b, const ushort* __restrict__ n2b,
    const int* __restrict__ gstart, float* __restrict__ S1,
    float* __restrict__ S2) {
    int g  = blockIdx.x >> 3;
    int ch = blockIdx.x & 7;
    int r0 = gstart[g], r1 = gstart[g + 1];
    int len = r1 - r0;
    if (len <= 0) return;
    int L = (len + 7) >> 3;
    int a = r0 + ch * L;
    int bnd = min(a + L, r1);
    if (a >= bnd) return;

    int tid = threadIdx.x;
    int mat = tid >> 7;          // 0: x1b->S1, 1: n2b->S2
    int rp  = (tid >> 6) & 1;    // row parity
    int cp  = tid & 63;          // col pair (2 bf16 per uint)
    const ushort* __restrict__ M = mat ? n2b : x1b;
    float ax = 0.f, ay = 0.f;
    for (int n = a + rp; n < bnd; n += 2) {
        uint v = *(const uint*)(M + (size_t)n * D + cp * 2);
        ax += __uint_as_float(v << 16);
        ay += __uint_as_float(v & 0xffff0000u);
    }
    float* __restrict__ S = mat ? S2 : S1;
    atomicAdd(&S[g * D + cp * 2], ax);
    atomicAdd(&S[g * D + cp * 2 + 1], ay);
}

// ---------------- final: hg = (S1@W2s + S2@W2n)/cnt + b2 ; out = hg@Wc + bc ----

__global__ void k_final(const float* __restrict__ S1, const float* __restrict__ S2,
                        const int* __restrict__ gstart, const float* __restrict__ W2s,
                        const float* __restrict__ W2n, const float* __restrict__ b2,
                        const float* __restrict__ Wc, const float* __restrict__ bc,
                        float* __restrict__ out) {
    __shared__ float s1[D], s2[D], hg[D];
    int g = blockIdx.x, c = threadIdx.x;
    s1[c] = S1[g * D + c];
    s2[c] = S2[g * D + c];
    __syncthreads();
    float acc = 0.f;
#pragma unroll 8
    for (int k = 0; k < D; k++) {
        acc = fmaf(s1[k], W2s[k * D + c], acc);
        acc = fmaf(s2[k], W2n[k * D + c], acc);
    }
    int cnt = gstart[g + 1] - gstart[g];
    hg[c] = (cnt > 0) ? (acc / (float)cnt + b2[c]) : 0.f;
    __syncthreads();
    if (c < N_CLS) {
        float o = bc[c];
        for (int k = 0; k < D; k++) o = fmaf(hg[k], Wc[k * N_CLS + c], o);
        out[g * N_CLS + c] = o;
    }
}

// ---------------- launch ----------------

extern "C" void kernel_launch(void* const* d_in, const int* in_sizes, int n_in,
                              void* d_out, int out_size, void* d_ws, size_t ws_size,
                              hipStream_t stream) {
    const float* h   = (const float*)d_in[0];
    const int*   src = (const int*)d_in[1];
    const int*   dst = (const int*)d_in[2];
    const int*   gid = (const int*)d_in[3];
    const float* W1s = (const float*)d_in[5];
    const float* W1n = (const float*)d_in[6];
    const float* b1  = (const float*)d_in[7];
    const float* W2s = (const float*)d_in[8];
    const float* W2n = (const float*)d_in[9];
    const float* b2  = (const float*)d_in[10];
    const float* Wc  = (const float*)d_in[11];
    const float* bc  = (const float*)d_in[12];
    float* out = (float*)d_out;

    const int N = in_sizes[0] / D;  // 100000
    const int E = in_sizes[1];      // 1600000

    char* w = (char*)d_ws;
    size_t off = 0;
    auto alloc = [&](size_t elems) -> void* {   // elems are 4-byte units
        void* p = w + off;
        off += elems * 4;
        return p;
    };
    // zero-initialized region first (one memset)
    float* S1     = (float*)alloc((size_t)N_GRAPHS * D);
    float* S2     = (float*)alloc((size_t)N_GRAPHS * D);
    int*   deg    = (int*)alloc(N);
    size_t zero_bytes = off;
    float* invdeg = (float*)alloc(N);
    int*   gstart = (int*)alloc(128);
    int*   slot   = (int*)alloc(E);
    int*   csrf   = (int*)alloc((size_t)N * SLOTS);   // 25.6 MB padded CSR
    ushort* fb    = (ushort*)alloc((size_t)N * 64);   // bf16 [N,128] h
    ushort* nbb   = (ushort*)alloc((size_t)N * 64);   // bf16 [N,128] neigh1 / neigh2
    ushort* x1b   = (ushort*)alloc((size_t)N * 64);   // bf16 [N,128] x1
    ushort* wT    = (ushort*)alloc(16384);            // bf16 [128 cols][256 k]
    (void)ws_size;

    hipMemsetAsync(d_ws, 0, zero_bytes, stream);

    int eb  = (E + 255) / 256;
    int nbk = (N + 255) / 256;
    int t4  = N * 32;  // float4 count of [N,128] f32
    int gq  = ((N + 3) / 4) * 4;   // quarter-split gather grid

    k_cast<<<(t4 + 255) / 256, 256, 0, stream>>>(h, fb, t4);
    k_castw<<<128, 256, 0, stream>>>(W1s, W1n, wT);
    k_degslot<<<eb, 256, 0, stream>>>(dst, deg, slot, E);
    k_prep<<<nbk, 256, 0, stream>>>(deg, invdeg, N);
    k_scatter<<<eb, 256, 0, stream>>>(src, dst, slot, csrf, E);
    k_gbound<<<1, 128, 0, stream>>>(gid, gstart, N);
    k_aggq<<<gq, 256, 0, stream>>>(fb, deg, csrf, invdeg, nbb, N);
    k_mm1m<<<(N + 127) / 128, 256, 0, stream>>>(fb, nbb, wT, b1, x1b, N);
    k_aggq<<<gq, 256, 0, stream>>>(x1b, deg, csrf, invdeg, nbb, N);
    k_gsum<<<N_GRAPHS * 8, 256, 0, stream>>>(x1b, nbb, gstart, S1, S2);
    k_final<<<N_GRAPHS, 128, 0, stream>>>(S1, S2, gstart, W2s, W2n, b2, Wc, bc, out);
}

// Round 9
// 426.314 us; speedup vs baseline: 1.3639x; 1.3639x over previous
//
#include <hip/hip_runtime.h>

#define D        128
#define N_GRAPHS 64
#define N_CLS    16
#define LDA      40   // mm1m LDS row stride in bf16 (80 B: 16B-aligned, 2-way banks = free)
#define SLOTS    64   // padded CSR width; deg ~ Poisson(16), max<<64

typedef unsigned int  uint;
typedef unsigned short ushort;
typedef __attribute__((ext_vector_type(8))) short short8;
typedef __attribute__((ext_vector_type(4))) float f32x4;

__device__ inline ushort f2b(float f) {   // f32 -> bf16 RNE
    uint u = __float_as_uint(f);
    u += 0x7fffu + ((u >> 16) & 1u);
    return (ushort)(u >> 16);
}

// ---------------- fused padded-CSR build ----------------
// atomic returns the slot; csrf written in the same kernel (no slot array,
// no second E-pass).

__global__ void k_build(const int* __restrict__ src, const int* __restrict__ dst,
                        int* __restrict__ deg, int* __restrict__ csrf, int E) {
    int e = blockIdx.x * 256 + threadIdx.x;
    if (e < E) {
        int dd = dst[e];
        int sl = atomicAdd(&deg[dd], 1);
        if (sl < SLOTS) csrf[(size_t)dd * SLOTS + sl] = src[e];
    }
}

__global__ void k_prep(const int* __restrict__ deg, float* __restrict__ invdeg, int N) {
    int i = blockIdx.x * 256 + threadIdx.x;
    if (i < N) {
        int d = deg[i];
        invdeg[i] = 1.0f / (float)(d > 1 ? d : 1);
    }
}

// graph boundaries from sorted gid: gstart[g] = lower_bound(gid, g)
__global__ void k_gbound(const int* __restrict__ gid, int* __restrict__ gstart, int N) {
    int g = threadIdx.x;
    if (g > N_GRAPHS) return;
    int lo = 0, hi = N;
    while (lo < hi) {
        int mid = (lo + hi) >> 1;
        if (gid[mid] < g) lo = mid + 1; else hi = mid;
    }
    gstart[g] = lo;
}

// ---------------- casts ----------------

__global__ void k_cast(const float* __restrict__ x, ushort* __restrict__ y, int total4) {
    int i = blockIdx.x * 256 + threadIdx.x;
    if (i < total4) {
        float4 v = ((const float4*)x)[i];
        ushort4 o;
        o.x = f2b(v.x); o.y = f2b(v.y); o.z = f2b(v.z); o.w = f2b(v.w);
        ((ushort4*)y)[i] = o;
    }
}

// wT[col][k] (k=0..255: Ws rows then Wn rows), bf16
__global__ void k_castw(const float* __restrict__ Ws, const float* __restrict__ Wn,
                        ushort* __restrict__ wT) {
    int i = blockIdx.x * 256 + threadIdx.x;   // 32768
    int c = i >> 8, k = i & 255;
    float v = (k < 128) ? Ws[k * 128 + c] : Wn[(k - 128) * 128 + c];
    wT[c * 256 + k] = f2b(v);
}

// ---------------- bf16 neighbor-mean gather: wave per node (full 256B rows) --
// lane = (ej 0..3, cg 0..15): 16 lanes cover one full row; 4 edges in flight,
// x2 unrolled = 8 outstanding row loads per wave. shfl_xor(16,32) reduces.

__global__ __launch_bounds__(256) void k_aggb(
    const ushort* __restrict__ fb, const int* __restrict__ deg,
    const int* __restrict__ csrf, const float* __restrict__ invdeg,
    ushort* __restrict__ outb, int N) {
    int lane = threadIdx.x & 63;
    int n = blockIdx.x * 4 + (threadIdx.x >> 6);
    if (n >= N) return;
    int d = deg[n];
    if (d > SLOTS) d = SLOTS;
    const int* __restrict__ lst = csrf + (size_t)n * SLOTS;
    int ej = lane >> 4;      // 0..3
    int cg = lane & 15;      // cols cg*8 .. cg*8+7

    float acc[8];
#pragma unroll
    for (int i = 0; i < 8; i++) acc[i] = 0.f;

    int e = ej;
    for (; e + 4 < d; e += 8) {
        int s0 = lst[e];
        int s1 = lst[e + 4];
        uint4 v0 = *(const uint4*)(fb + (size_t)s0 * D + cg * 8);
        uint4 v1 = *(const uint4*)(fb + (size_t)s1 * D + cg * 8);
        acc[0] += __uint_as_float(v0.x << 16);
        acc[1] += __uint_as_float(v0.x & 0xffff0000u);
        acc[2] += __uint_as_float(v0.y << 16);
        acc[3] += __uint_as_float(v0.y & 0xffff0000u);
        acc[4] += __uint_as_float(v0.z << 16);
        acc[5] += __uint_as_float(v0.z & 0xffff0000u);
        acc[6] += __uint_as_float(v0.w << 16);
        acc[7] += __uint_as_float(v0.w & 0xffff0000u);
        acc[0] += __uint_as_float(v1.x << 16);
        acc[1] += __uint_as_float(v1.x & 0xffff0000u);
        acc[2] += __uint_as_float(v1.y << 16);
        acc[3] += __uint_as_float(v1.y & 0xffff0000u);
        acc[4] += __uint_as_float(v1.z << 16);
        acc[5] += __uint_as_float(v1.z & 0xffff0000u);
        acc[6] += __uint_as_float(v1.w << 16);
        acc[7] += __uint_as_float(v1.w & 0xffff0000u);
    }
    for (; e < d; e += 4) {
        int s = lst[e];
        uint4 v = *(const uint4*)(fb + (size_t)s * D + cg * 8);
        acc[0] += __uint_as_float(v.x << 16);
        acc[1] += __uint_as_float(v.x & 0xffff0000u);
        acc[2] += __uint_as_float(v.y << 16);
        acc[3] += __uint_as_float(v.y & 0xffff0000u);
        acc[4] += __uint_as_float(v.z << 16);
        acc[5] += __uint_as_float(v.z & 0xffff0000u);
        acc[6] += __uint_as_float(v.w << 16);
        acc[7] += __uint_as_float(v.w & 0xffff0000u);
    }
#pragma unroll
    for (int i = 0; i < 8; i++) {
        acc[i] += __shfl_xor(acc[i], 16);
        acc[i] += __shfl_xor(acc[i], 32);
    }
    if (ej == 0) {
        float id = invdeg[n];
        uint4 o;
        o.x = (uint)f2b(acc[0] * id) | ((uint)f2b(acc[1] * id) << 16);
        o.y = (uint)f2b(acc[2] * id) | ((uint)f2b(acc[3] * id) << 16);
        o.z = (uint)f2b(acc[4] * id) | ((uint)f2b(acc[5] * id) << 16);
        o.w = (uint)f2b(acc[6] * id) | ((uint)f2b(acc[7] * id) << 16);
        *(uint4*)(outb + (size_t)n * D + cg * 8) = o;
    }
}

// ---------------- layer-1 GEMM via MFMA (bf16 in, bf16 out) ----------------

__global__ __launch_bounds__(256, 2) void k_mm1m(
    const ushort* __restrict__ hb, const ushort* __restrict__ nbb,
    const ushort* __restrict__ wT, const float* __restrict__ b,
    ushort* __restrict__ x1b, int N) {
    __shared__ __align__(16) ushort As[128 * LDA];
    __shared__ __align__(16) ushort Bs[128 * LDA];
    int t    = threadIdx.x;
    int w    = t >> 6;
    int lane = t & 63;
    int m    = lane & 15;
    int quad = lane >> 4;
    int n0   = blockIdx.x * 128;

    f32x4 acc[2][8];
#pragma unroll
    for (int rt = 0; rt < 2; rt++)
#pragma unroll
        for (int ct = 0; ct < 8; ct++) acc[rt][ct] = (f32x4){0.f, 0.f, 0.f, 0.f};

#pragma unroll 1
    for (int kc = 0; kc < 8; kc++) {
        int k0 = kc * 32;
        const ushort* __restrict__ A = (k0 < 128) ? hb : nbb;
        int ka = k0 & 127;
        __syncthreads();
#pragma unroll
        for (int i = 0; i < 2; i++) {
            int linear = i * 256 + t;       // 0..511
            int row = linear >> 2;
            int q   = linear & 3;
            int nn = n0 + row;
            uint4 v = make_uint4(0u, 0u, 0u, 0u);
            if (nn < N) v = *(const uint4*)(A + (size_t)nn * D + ka + q * 8);
            *(uint4*)(&As[row * LDA + q * 8]) = v;
        }
#pragma unroll
        for (int i = 0; i < 2; i++) {
            int linear = i * 256 + t;
            int col = linear >> 2;
            int q   = linear & 3;
            uint4 v = *(const uint4*)(wT + (size_t)col * 256 + k0 + q * 8);
            *(uint4*)(&Bs[col * LDA + q * 8]) = v;
        }
        __syncthreads();
        short8 af[2], bf[8];
#pragma unroll
        for (int rt = 0; rt < 2; rt++)
            af[rt] = *(const short8*)(&As[(w * 32 + rt * 16 + m) * LDA + quad * 8]);
#pragma unroll
        for (int ct = 0; ct < 8; ct++)
            bf[ct] = *(const short8*)(&Bs[(ct * 16 + m) * LDA + quad * 8]);
#pragma unroll
        for (int rt = 0; rt < 2; rt++)
#pragma unroll
            for (int ct = 0; ct < 8; ct++)
                acc[rt][ct] = __builtin_amdgcn_mfma_f32_16x16x32_bf16(
                    af[rt], bf[ct], acc[rt][ct], 0, 0, 0);
    }
#pragma unroll
    for (int ct = 0; ct < 8; ct++) {
        float bias = b[ct * 16 + m];
#pragma unroll
        for (int rt = 0; rt < 2; rt++) {
#pragma unroll
            for (int r = 0; r < 4; r++) {
                int n = n0 + w * 32 + rt * 16 + quad * 4 + r;
                if (n < N)
                    x1b[(size_t)n * D + ct * 16 + m] =
                        f2b(fmaxf(acc[rt][ct][r] + bias, 0.f));
            }
        }
    }
}

// ---------------- per-graph sums: contention-free via gstart ----------------

__global__ __launch_bounds__(256) void k_gsum(
    const ushort* __restrict__ x1b, const ushort* __restrict__ n2b,
    const int* __restrict__ gstart, float* __restrict__ S1,
    float* __restrict__ S2) {
    int g  = blockIdx.x >> 3;
    int ch = blockIdx.x & 7;
    int r0 = gstart[g], r1 = gstart[g + 1];
    int len = r1 - r0;
    if (len <= 0) return;
    int L = (len + 7) >> 3;
    int a = r0 + ch * L;
    int bnd = min(a + L, r1);
    if (a >= bnd) return;

    int tid = threadIdx.x;
    int mat = tid >> 7;          // 0: x1b->S1, 1: n2b->S2
    int rp  = (tid >> 6) & 1;    // row parity
    int cp  = tid & 63;          // col pair (2 bf16 per uint)
    const ushort* __restrict__ M = mat ? n2b : x1b;
    float ax = 0.f, ay = 0.f;
    for (int n = a + rp; n < bnd; n += 2) {
        uint v = *(const uint*)(M + (size_t)n * D + cp * 2);
        ax += __uint_as_float(v << 16);
        ay += __uint_as_float(v & 0xffff0000u);
    }
    float* __restrict__ S = mat ? S2 : S1;
    atomicAdd(&S[g * D + cp * 2], ax);
    atomicAdd(&S[g * D + cp * 2 + 1], ay);
}

// ---------------- final: hg = (S1@W2s + S2@W2n)/cnt + b2 ; out = hg@Wc + bc ----

__global__ void k_final(const float* __restrict__ S1, const float* __restrict__ S2,
                        const int* __restrict__ gstart, const float* __restrict__ W2s,
                        const float* __restrict__ W2n, const float* __restrict__ b2,
                        const float* __restrict__ Wc, const float* __restrict__ bc,
                        float* __restrict__ out) {
    __shared__ float s1[D], s2[D], hg[D];
    int g = blockIdx.x, c = threadIdx.x;
    s1[c] = S1[g * D + c];
    s2[c] = S2[g * D + c];
    __syncthreads();
    float acc = 0.f;
#pragma unroll 8
    for (int k = 0; k < D; k++) {
        acc = fmaf(s1[k], W2s[k * D + c], acc);
        acc = fmaf(s2[k], W2n[k * D + c], acc);
    }
    int cnt = gstart[g + 1] - gstart[g];
    hg[c] = (cnt > 0) ? (acc / (float)cnt + b2[c]) : 0.f;
    __syncthreads();
    if (c < N_CLS) {
        float o = bc[c];
        for (int k = 0; k < D; k++) o = fmaf(hg[k], Wc[k * N_CLS + c], o);
        out[g * N_CLS + c] = o;
    }
}

// ---------------- launch ----------------

extern "C" void kernel_launch(void* const* d_in, const int* in_sizes, int n_in,
                              void* d_out, int out_size, void* d_ws, size_t ws_size,
                              hipStream_t stream) {
    const float* h   = (const float*)d_in[0];
    const int*   src = (const int*)d_in[1];
    const int*   dst = (const int*)d_in[2];
    const int*   gid = (const int*)d_in[3];
    const float* W1s = (const float*)d_in[5];
    const float* W1n = (const float*)d_in[6];
    const float* b1  = (const float*)d_in[7];
    const float* W2s = (const float*)d_in[8];
    const float* W2n = (const float*)d_in[9];
    const float* b2  = (const float*)d_in[10];
    const float* Wc  = (const float*)d_in[11];
    const float* bc  = (const float*)d_in[12];
    float* out = (float*)d_out;

    const int N = in_sizes[0] / D;  // 100000
    const int E = in_sizes[1];      // 1600000

    char* w = (char*)d_ws;
    size_t off = 0;
    auto alloc = [&](size_t elems) -> void* {   // elems are 4-byte units
        void* p = w + off;
        off += elems * 4;
        return p;
    };
    // zero-initialized region first (one memset)
    float* S1     = (float*)alloc((size_t)N_GRAPHS * D);
    float* S2     = (float*)alloc((size_t)N_GRAPHS * D);
    int*   deg    = (int*)alloc(N);
    size_t zero_bytes = off;
    float* invdeg = (float*)alloc(N);
    int*   gstart = (int*)alloc(128);
    int*   csrf   = (int*)alloc((size_t)N * SLOTS);   // 25.6 MB padded CSR
    ushort* fb    = (ushort*)alloc((size_t)N * 64);   // bf16 [N,128] h
    ushort* nbb   = (ushort*)alloc((size_t)N * 64);   // bf16 [N,128] neigh1 / neigh2
    ushort* x1b   = (ushort*)alloc((size_t)N * 64);   // bf16 [N,128] x1
    ushort* wT    = (ushort*)alloc(16384);            // bf16 [128 cols][256 k]
    (void)ws_size;

    hipMemsetAsync(d_ws, 0, zero_bytes, stream);

    int eb  = (E + 255) / 256;
    int nbk = (N + 255) / 256;
    int t4  = N * 32;  // float4 count of [N,128] f32

    k_cast<<<(t4 + 255) / 256, 256, 0, stream>>>(h, fb, t4);
    k_castw<<<128, 256, 0, stream>>>(W1s, W1n, wT);
    k_build<<<eb, 256, 0, stream>>>(src, dst, deg, csrf, E);
    k_prep<<<nbk, 256, 0, stream>>>(deg, invdeg, N);
    k_gbound<<<1, 128, 0, stream>>>(gid, gstart, N);
    k_aggb<<<(N + 3) / 4, 256, 0, stream>>>(fb, deg, csrf, invdeg, nbb, N);
    k_mm1m<<<(N + 127) / 128, 256, 0, stream>>>(fb, nbb, wT, b1, x1b, N);
    k_aggb<<<(N + 3) / 4, 256, 0, stream>>>(x1b, deg, csrf, invdeg, nbb, N);
    k_gsum<<<N_GRAPHS * 8, 256, 0, stream>>>(x1b, nbb, gstart, S1, S2);
    k_final<<<N_GRAPHS, 128, 0, stream>>>(S1, S2, gstart, W2s, W2n, b2, Wc, bc, out);
}